// Round 14
// baseline (199.527 us; speedup 1.0000x reference)
//
#include <hip/hip_runtime.h>
#include <hip/hip_bf16.h>
#include <stdint.h>

// Problem constants: b=2, s=2048, d=1024, H=16, DH=64, inner=1024
// External tensors FP32; internal bf16 MFMA.
#define NH     16
#define DHEAD  64
#define SEQ    2048
#define DMODEL 1024
#define NBATCH 2
#define INNER  1024
#define QKVN   3072
#define ROWS   4096      // NBATCH*SEQ
#define ATT_QB 64        // q rows per block (2 q-halves x 2 kv-halves, 4 waves)
#define ATT_KB 64        // kv rows per iteration

typedef __attribute__((ext_vector_type(8))) __bf16 bf16x8;
typedef __attribute__((ext_vector_type(4))) float floatx4;
typedef __attribute__((ext_vector_type(16))) float floatx16;

__device__ __forceinline__ unsigned short f2bf(float f) {
    union { __bf16 b; unsigned short u; } c; c.b = (__bf16)f; return c.u;
}

__device__ __forceinline__ unsigned int pk2(float lo, float hi) {
    union { ushort2 s; unsigned int u; } c;
    c.s.x = f2bf(lo); c.s.y = f2bf(hi); return c.u;
}

__device__ __forceinline__ float fexp2(float x) {
#if __has_builtin(__builtin_amdgcn_exp2f)
    return __builtin_amdgcn_exp2f(x);
#else
    float r; asm("v_exp_f32 %0, %1" : "=v"(r) : "v"(x)); return r;
#endif
}

typedef __attribute__((address_space(1))) void gvoid;
typedef __attribute__((address_space(3))) void lvoid;
__device__ __forceinline__ void gl_lds16(const void* g, void* l) {
    __builtin_amdgcn_global_load_lds((gvoid*)g, (lvoid*)l, 16, 0, 0);
}

// ------- fused prep: 2 weight transposes (fp32->bf16) + layernorm ---------------
// z=0: wqkv [1024,3072] -> wqkvT (x<96); z=1: wout [1024,1024] -> woutT (x<32);
// z=2: layernorm row = y*128+x over all 4096 rows. One launch instead of two.
__global__ __launch_bounds__(256) void prep_kernel(
        const float* __restrict__ x,
        const float* __restrict__ gamma,
        const float* __restrict__ beta,
        unsigned short* __restrict__ xn,
        const float* __restrict__ wqkv, unsigned short* __restrict__ wqkvT,
        const float* __restrict__ wout, unsigned short* __restrict__ woutT) {
    __shared__ unsigned short tile[32][33];
    __shared__ float red[4][2];
    const int t = threadIdx.x;
    if (blockIdx.z == 2) {
        // ---- layernorm fp32 -> bf16 ----
        const int row = blockIdx.y * 128 + blockIdx.x;
        const size_t base = (size_t)row * DMODEL + t * 4;
        float4 v = *(const float4*)(x + base);
        float s  = v.x + v.y + v.z + v.w;
        float ss = v.x*v.x + v.y*v.y + v.z*v.z + v.w*v.w;
        for (int off = 32; off >= 1; off >>= 1) {
            s  += __shfl_xor(s,  off);
            ss += __shfl_xor(ss, off);
        }
        const int w = t >> 6, lane = t & 63;
        if (lane == 0) { red[w][0] = s; red[w][1] = ss; }
        __syncthreads();
        if (t == 0) {
            float S  = red[0][0] + red[1][0] + red[2][0] + red[3][0];
            float SS = red[0][1] + red[1][1] + red[2][1] + red[3][1];
            float mu  = S * (1.f / DMODEL);
            float var = SS * (1.f / DMODEL) - mu * mu;
            red[0][0] = mu; red[0][1] = rsqrtf(var + 1e-5f);
        }
        __syncthreads();
        const float mu = red[0][0], rstd = red[0][1];
        float4 g = *(const float4*)(gamma + t * 4);
        float4 bb = *(const float4*)(beta + t * 4);
        ushort4 o;
        o.x = f2bf((v.x - mu) * rstd * g.x + bb.x);
        o.y = f2bf((v.y - mu) * rstd * g.y + bb.y);
        o.z = f2bf((v.z - mu) * rstd * g.z + bb.z);
        o.w = f2bf((v.w - mu) * rstd * g.w + bb.w);
        *(ushort4*)(xn + base) = o;
        return;
    }
    // ---- transpose + fp32->bf16: out[c][r] = bf16(in[r][c]) ----
    const float* in; unsigned short* out; int rows, cols;
    if (blockIdx.z == 0) {
        if (blockIdx.x >= QKVN / 32) return;
        in = wqkv; out = wqkvT; rows = DMODEL; cols = QKVN;
    } else {
        if (blockIdx.x >= DMODEL / 32) return;
        in = wout; out = woutT; rows = INNER; cols = DMODEL;
    }
    const int bx = blockIdx.x * 32, by = blockIdx.y * 32;
    const int tx = t & 31, ty = t >> 5;
    for (int i = ty; i < 32; i += 8)
        tile[i][tx] = f2bf(in[(size_t)(by + i) * cols + bx + tx]);
    __syncthreads();
    for (int i = ty; i < 32; i += 8)
        out[(size_t)(bx + i) * rows + by + tx] = tile[tx][i];
}

// ------- QKV GEMM: 128x128 tile, BK=32, 3-buffer depth-2 prefetch (T4+T5) -------
// Counted-vmcnt pipeline (r12, proven -7us): raw s_barrier; each wave waits its
// OWN vmcnt(4) for the tile it is about to read BEFORE the barrier -- the newest
// prefetch (4 loads) stays in flight across it. Depth-2 into 3 rotating buffers.
// ds_read fragments issued FIRST after the barrier, stage(kk+2) after, T5
// setprio(1) around the MFMA cluster (null-measured r13, harmless).
// LDS = 48KB -> 3 blocks/CU; grid 768 = exactly 3/CU.
__global__ __launch_bounds__(256) void gemm_qkv(
        const unsigned short* __restrict__ A,    // xn [4096,1024]
        const unsigned short* __restrict__ Bt,   // wqkvT [3072,1024]
        unsigned short* __restrict__ qP,
        unsigned short* __restrict__ kP,
        unsigned short* __restrict__ vT) {
    const int K = DMODEL;
    __shared__ __align__(16) unsigned short smem[3 * 8192];  // 48KB: 3 x (A 4096 + B 4096)
    const int t = threadIdx.x;
    const int mBase = blockIdx.y * 128, nBase = blockIdx.x * 128;
    const int w = t >> 6, lane = t & 63, quad = lane >> 4, l16 = lane & 15;
    const int wm = (w >> 1) * 64, wn = (w & 1) * 64;
    const int srow = t >> 2, sch = t & 3;
    floatx4 acc[4][4];
    for (int mi = 0; mi < 4; mi++)
        for (int ni = 0; ni < 4; ni++) acc[mi][ni] = (floatx4)0.f;

    auto stage = [&](int k0, int bi) {      // 4 gl_lds16 per wave (A0,B0,A1,B1)
        unsigned short* sA = smem + bi * 8192;
        unsigned short* sB = sA + 4096;
        #pragma unroll
        for (int c = 0; c < 2; c++) {
            const int row = c * 64 + srow;
            const int gcol = (sch ^ ((row >> 1) & 3)) * 8;
            gl_lds16(&A[(size_t)(mBase + row) * K + k0 + gcol], &sA[(c * 256 + w * 64) * 8]);
            gl_lds16(&Bt[(size_t)(nBase + row) * K + k0 + gcol], &sB[(c * 256 + w * 64) * 8]);
        }
    };

    const int NK = K / 32;                  // 32
    stage(0, 0);
    stage(32, 1);
    for (int kk = 0; kk < NK; ++kk) {
        // own stage(kk) landed; newest prefetch (4 loads) stays in flight
        if (kk + 1 < NK) { asm volatile("s_waitcnt vmcnt(4)" ::: "memory"); }
        else             { asm volatile("s_waitcnt vmcnt(0)" ::: "memory"); }
        __builtin_amdgcn_sched_barrier(0);
        __builtin_amdgcn_s_barrier();
        const unsigned short* sA = smem + (kk % 3) * 8192;
        const unsigned short* sB = sA + 4096;
        bf16x8 af[4], bfv[4];
        #pragma unroll
        for (int mi = 0; mi < 4; mi++) {
            const int r = wm + mi * 16 + l16;
            af[mi] = *(const bf16x8*)&sA[r * 32 + (quad ^ ((r >> 1) & 3)) * 8];
        }
        #pragma unroll
        for (int ni = 0; ni < 4; ni++) {
            const int r = wn + ni * 16 + l16;
            bfv[ni] = *(const bf16x8*)&sB[r * 32 + (quad ^ ((r >> 1) & 3)) * 8];
        }
        if (kk + 2 < NK) stage((kk + 2) * 32, (kk + 2) % 3);
        __builtin_amdgcn_s_setprio(1);
        #pragma unroll
        for (int mi = 0; mi < 4; mi++)
            #pragma unroll
            for (int ni = 0; ni < 4; ni++)
                acc[mi][ni] = __builtin_amdgcn_mfma_f32_16x16x32_bf16(
                    af[mi], bfv[ni], acc[mi][ni], 0, 0, 0);
        __builtin_amdgcn_s_setprio(0);
    }
    __syncthreads();                        // all reads done before epilogue overlay
    const int reg = nBase >> 10;                  // block-uniform: 0=q 1=k 2=v
    if (reg == 2) {
        #pragma unroll
        for (int ni = 0; ni < 4; ni++) {
            const int col = nBase + wn + ni * 16 + l16;
            const int h = (col & 1023) >> 6, dh = col & 63;
            #pragma unroll
            for (int mi = 0; mi < 4; mi++) {
                const int row0 = mBase + wm + mi * 16 + quad * 4;
                const int b = row0 >> 11, s0 = row0 & 2047;
                ushort4 o;
                o.x = f2bf(acc[mi][ni][0]); o.y = f2bf(acc[mi][ni][1]);
                o.z = f2bf(acc[mi][ni][2]); o.w = f2bf(acc[mi][ni][3]);
                *(ushort4*)&vT[((size_t)(b * NH + h) * DHEAD + dh) * SEQ + s0] = o;
            }
        }
    } else {
        unsigned short* dst = (reg == 0) ? qP : kP;
        // fold DHEAD^-0.5 * log2(e) into q so attn softmax is a bare v_exp_f32
        const float scl = (reg == 0) ? 0.18033688011112042f : 1.f;
        const int hh = ((nBase + wn) & 1023) >> 6;     // wave-uniform head
        // 4 per-wave tb buffers (36.9KB) overlay the retired 48KB staging LDS.
        unsigned short* tb_ = smem + w * (64 * 72);
        #pragma unroll
        for (int mi = 0; mi < 4; mi++)
            #pragma unroll
            for (int ni = 0; ni < 4; ni++)
                #pragma unroll
                for (int i = 0; i < 4; i++)
                    tb_[(mi * 16 + quad * 4 + i) * 72 + ni * 16 + l16] =
                        f2bf(acc[mi][ni][i] * scl);
        asm volatile("s_waitcnt lgkmcnt(0)" ::: "memory");   // own-wave tb writes done
        const int row_g = mBase + wm + lane;
        const int b = row_g >> 11, sr = row_g & 2047;
        unsigned short* orow = dst + ((size_t)(b * NH + hh) * SEQ + sr) * DHEAD;
        #pragma unroll
        for (int c = 0; c < 8; c++)
            *(bf16x8*)&orow[c * 8] = *(const bf16x8*)&tb_[lane * 72 + c * 8];
    }
}

// ------- out GEMM: C = A*Bt^T + bias (fp32), 64x64 tile, BK=32, 3-buffer T4 ----
// RETILE (r14): 128x64@512blocks gave only 2 blocks/CU = 8 waves/CU --
// occupancy-starved (same diagnosis as r1 attn). 64x64 tiles -> grid (16,64) =
// 1024 blocks = 4 blocks/CU = 16 waves/CU, LDS 24KB. Per wave: 32x32 output,
// acc[2][2], 4 MFMA / 4 ds_read per K-step. Staging: exactly 1 load/thread per
// operand (lane-linear LDS dest sA + w*512); vmcnt(2) counted wait, depth-2.
__global__ __launch_bounds__(256) void gemm_out(
        const unsigned short* __restrict__ A,
        const unsigned short* __restrict__ Bt,
        float* __restrict__ C,
        const int M, const int N, const int K,
        const float* __restrict__ bias) {
    __shared__ __align__(16) unsigned short smem[3 * 4096];  // 24KB: 3 x (A 2048 + B 2048)
    const int t = threadIdx.x;
    const int mBase = blockIdx.y * 64, nBase = blockIdx.x * 64;
    const int w = t >> 6, lane = t & 63, quad = lane >> 4, l16 = lane & 15;
    const int wm = (w >> 1) * 32, wn = (w & 1) * 32;
    const int srow = t >> 2, sch = t & 3;    // srow = w*16 + (lane>>2)
    floatx4 acc[2][2];
    for (int mi = 0; mi < 2; mi++)
        for (int ni = 0; ni < 2; ni++) acc[mi][ni] = (floatx4)0.f;

    auto stage = [&](int k0, int bi) {      // 2 gl_lds16 per thread (A, B)
        unsigned short* sA = smem + bi * 4096;
        unsigned short* sB = sA + 2048;
        const int gcol = (sch ^ ((srow >> 1) & 3)) * 8;
        gl_lds16(&A[(size_t)(mBase + srow) * K + k0 + gcol], &sA[w * 512]);
        gl_lds16(&Bt[(size_t)(nBase + srow) * K + k0 + gcol], &sB[w * 512]);
    };

    const int NK = K / 32;
    stage(0, 0);
    stage(32, 1);
    for (int kk = 0; kk < NK; ++kk) {
        if (kk + 1 < NK) { asm volatile("s_waitcnt vmcnt(2)" ::: "memory"); }
        else             { asm volatile("s_waitcnt vmcnt(0)" ::: "memory"); }
        __builtin_amdgcn_sched_barrier(0);
        __builtin_amdgcn_s_barrier();
        const unsigned short* sA = smem + (kk % 3) * 4096;
        const unsigned short* sB = sA + 2048;
        bf16x8 af[2], bfv[2];
        #pragma unroll
        for (int mi = 0; mi < 2; mi++) {
            const int r = wm + mi * 16 + l16;
            af[mi] = *(const bf16x8*)&sA[r * 32 + (quad ^ ((r >> 1) & 3)) * 8];
        }
        #pragma unroll
        for (int ni = 0; ni < 2; ni++) {
            const int r = wn + ni * 16 + l16;
            bfv[ni] = *(const bf16x8*)&sB[r * 32 + (quad ^ ((r >> 1) & 3)) * 8];
        }
        if (kk + 2 < NK) stage((kk + 2) * 32, (kk + 2) % 3);
        __builtin_amdgcn_s_setprio(1);
        #pragma unroll
        for (int mi = 0; mi < 2; mi++)
            #pragma unroll
            for (int ni = 0; ni < 2; ni++)
                acc[mi][ni] = __builtin_amdgcn_mfma_f32_16x16x32_bf16(
                    af[mi], bfv[ni], acc[mi][ni], 0, 0, 0);
        __builtin_amdgcn_s_setprio(0);
    }
    #pragma unroll
    for (int mi = 0; mi < 2; mi++)
        #pragma unroll
        for (int ni = 0; ni < 2; ni++) {
            const int col = nBase + wn + ni * 16 + l16;
            const float badd = bias ? bias[col] : 0.f;
            #pragma unroll
            for (int i = 0; i < 4; i++) {
                const int row = mBase + wm + mi * 16 + quad * 4 + i;
                C[(size_t)row * N + col] = acc[mi][ni][i] + badd;
            }
        }
}

// ------- flash attention: 32x32 MFMA + in-reg P + KV-split 4-wave blocks --------
// (round-6 kernel, converged at ~58us -- kept byte-identical)
__global__ __launch_bounds__(256, 4) void attn_kernel(
        const unsigned short* __restrict__ qP,
        const unsigned short* __restrict__ kP,
        const unsigned short* __restrict__ vT,
        unsigned short* __restrict__ aout) {   // [4096][1024] bf16
    __shared__ __align__(16) unsigned short sK[2][ATT_KB * 64];
    __shared__ __align__(16) unsigned short sV[2][ATT_KB * 64];
    const int t = threadIdx.x, w = t >> 6, lane = t & 63;
    const int l32 = lane & 31, half = lane >> 5;
    const int qh = w & 1, kh = w >> 1;
    const int bid = blockIdx.x;                  // grid is 1024, 1-D
    const int xcd = bid & 7, slot = bid >> 3;    // 128 slots per XCD
    const int bh = xcd * 4 + (slot >> 5);        // 4 bh per XCD
    const int qb = slot & 31;
    const int b = bh >> 4, h = bh & 15;
    const int qbase = qb * ATT_QB + qh * 32;

    bf16x8 qf[4];
    #pragma unroll
    for (int kd = 0; kd < 4; kd++)
        qf[kd] = *(const bf16x8*)&qP[
            ((size_t)bh * SEQ + qbase + l32) * DHEAD + kd * 16 + half * 8];

    floatx16 oac[2];
    oac[0] = (floatx16)0.f; oac[1] = (floatx16)0.f;
    float lS = 0.f;

    const unsigned short* kb = kP + (size_t)bh * SEQ * DHEAD;
    const unsigned short* vb = vT + (size_t)bh * DHEAD * SEQ;
    const int r8 = lane >> 3, sw8 = ((lane & 7) ^ r8) * 8;

    auto stage = [&](int it, int bi) {
        const int kv0 = it * ATT_KB;
        #pragma unroll
        for (int ii = 0; ii < 2; ii++) {
            const int row = w * 16 + ii * 8 + r8;   // local row (row&7==r8)
            gl_lds16(kb + (size_t)(kv0 + row) * DHEAD + sw8,
                     (void*)&sK[bi][(w * 16 + ii * 8) * 64]);
            gl_lds16(vb + (size_t)row * SEQ + kv0 + sw8,
                     (void*)&sV[bi][(w * 16 + ii * 8) * 64]);
        }
    };
    stage(0, 0);

    const int NIT = SEQ / ATT_KB;      // 32
    for (int it = 0; it < NIT; ++it) {
        __syncthreads();               // staging of tile `it` landed (all waves)
        const int bi = it & 1;
        if (it + 1 < NIT) stage(it + 1, bi ^ 1);   // writes buf^1: disjoint

        bf16x8 kf[4];
        #pragma unroll
        for (int kd = 0; kd < 4; kd++) {
            const int r = kh * 32 + l32;
            kf[kd] = *(const bf16x8*)&sK[bi][r * 64 + 8 * ((2 * kd + half) ^ (l32 & 7))];
        }

        floatx16 sv = (floatx16)0.f;
        __builtin_amdgcn_s_setprio(1);
        #pragma unroll
        for (int kd = 0; kd < 4; kd++)
            sv = __builtin_amdgcn_mfma_f32_32x32x16_bf16(kf[kd], qf[kd], sv, 0, 0, 0);
        __builtin_amdgcn_s_setprio(0);

        float p[16];
        #pragma unroll
        for (int i = 0; i < 16; i++) p[i] = fexp2(sv[i]);
        {
            float s = 0.f;
            #pragma unroll
            for (int i = 0; i < 16; i++) s += p[i];
            s += __shfl_xor(s, 32);    // partner half covers the other 16 rows
            lS += s;
        }

        bf16x8 pf[2];
        #pragma unroll
        for (int kd = 0; kd < 2; kd++) {
            const int base = kd * 8;
            unsigned int c01 = pk2(p[base + 0], p[base + 1]);
            unsigned int c23 = pk2(p[base + 2], p[base + 3]);
            unsigned int c45 = pk2(p[base + 4], p[base + 5]);
            unsigned int c67 = pk2(p[base + 6], p[base + 7]);
            asm("v_permlane32_swap_b32 %0, %1" : "+v"(c01), "+v"(c45));
            asm("v_permlane32_swap_b32 %0, %1" : "+v"(c23), "+v"(c67));
            union { unsigned int u[4]; bf16x8 v; } fr;
            fr.u[0] = c01; fr.u[1] = c23; fr.u[2] = c45; fr.u[3] = c67;
            pf[kd] = fr.v;
        }

        __builtin_amdgcn_s_setprio(1);
        #pragma unroll
        for (int dt = 0; dt < 2; dt++)
            #pragma unroll
            for (int kd = 0; kd < 2; kd++) {
                const int r = dt * 32 + l32;
                bf16x8 vf = *(const bf16x8*)&sV[bi][
                    r * 64 + 8 * ((kh * 4 + kd * 2 + half) ^ (l32 & 7))];
                oac[dt] = __builtin_amdgcn_mfma_f32_32x32x16_bf16(vf, pf[kd], oac[dt], 0, 0, 0);
            }
        __builtin_amdgcn_s_setprio(0);
    }

    __syncthreads();
    float* redO = (float*)&sK[0][0];   // [2 qh][64 lanes][32 f32] = 16KB (== sK)
    float* redL = (float*)&sV[0][0];   // [2 qh][32 q] f32
    if (kh == 1) {
        #pragma unroll
        for (int dt = 0; dt < 2; dt++)
            #pragma unroll
            for (int g = 0; g < 4; g++) {
                const int c = dt * 4 + g;
                float4 o4;
                o4.x = oac[dt][g * 4 + 0]; o4.y = oac[dt][g * 4 + 1];
                o4.z = oac[dt][g * 4 + 2]; o4.w = oac[dt][g * 4 + 3];
                *(float4*)&redO[((size_t)qh * 64 + lane) * 32 + 4 * (c ^ (lane & 7))] = o4;
            }
        if (half == 0) redL[qh * 32 + l32] = lS;
    }
    __syncthreads();
    if (kh == 0) {
        #pragma unroll
        for (int dt = 0; dt < 2; dt++)
            #pragma unroll
            for (int g = 0; g < 4; g++) {
                const int c = dt * 4 + g;
                float4 o4 = *(const float4*)&redO[
                    ((size_t)qh * 64 + lane) * 32 + 4 * (c ^ (lane & 7))];
                oac[dt][g * 4 + 0] += o4.x; oac[dt][g * 4 + 1] += o4.y;
                oac[dt][g * 4 + 2] += o4.z; oac[dt][g * 4 + 3] += o4.w;
            }
        lS += redL[qh * 32 + l32];
        const float rl = 1.f / lS;
        unsigned short* orow = aout + ((size_t)(b * SEQ + qbase + l32)) * INNER + h * DHEAD;
        #pragma unroll
        for (int dt = 0; dt < 2; dt++)
            #pragma unroll
            for (int g = 0; g < 4; g++) {
                ushort4 o;
                o.x = f2bf(oac[dt][g * 4 + 0] * rl);
                o.y = f2bf(oac[dt][g * 4 + 1] * rl);
                o.z = f2bf(oac[dt][g * 4 + 2] * rl);
                o.w = f2bf(oac[dt][g * 4 + 3] * rl);
                *(ushort4*)&orow[dt * 32 + g * 8 + half * 4] = o;
            }
    }
}

extern "C" void kernel_launch(void* const* d_in, const int* in_sizes, int n_in,
                              void* d_out, int out_size, void* d_ws, size_t ws_size,
                              hipStream_t stream) {
    const float* x     = (const float*)d_in[0];
    const float* gamma = (const float*)d_in[1];
    const float* beta  = (const float*)d_in[2];
    const float* wqkv  = (const float*)d_in[3];
    const float* wout  = (const float*)d_in[4];
    const float* bout  = (const float*)d_in[5];
    float* out = (float*)d_out;

    unsigned short* ws     = (unsigned short*)d_ws;
    unsigned short* xn     = ws;                                  // 4096x1024
    unsigned short* wqkvT  = xn     + (size_t)ROWS * DMODEL;      // 3072x1024
    unsigned short* qPb    = wqkvT  + (size_t)QKVN * DMODEL;      // 32x2048x64
    unsigned short* kPb    = qPb    + (size_t)NBATCH * NH * SEQ * DHEAD;
    unsigned short* vTb    = kPb    + (size_t)NBATCH * NH * SEQ * DHEAD;
    unsigned short* attnO  = vTb    + (size_t)NBATCH * NH * SEQ * DHEAD; // 4096x1024
    unsigned short* woutT  = attnO  + (size_t)ROWS * INNER;       // 1024x1024

    // z=0: wqkv transpose (x<96); z=1: wout transpose (x<32); z=2: LN (128x32=4096 rows)
    prep_kernel<<<dim3(128, 32, 3), 256, 0, stream>>>(
        x, gamma, beta, xn, wqkv, wqkvT, wout, woutT);
    gemm_qkv<<<dim3(QKVN / 128, ROWS / 128), 256, 0, stream>>>(xn, wqkvT, qPb, kPb, vTb);
    attn_kernel<<<dim3((SEQ / ATT_QB) * NBATCH * NH), 256, 0, stream>>>(
        qPb, kPb, vTb, attnO);
    gemm_out<<<dim3(DMODEL / 64, ROWS / 64), 256, 0, stream>>>(
        attnO, woutT, out, ROWS, DMODEL, INNER, bout);
}

// Round 15
// 192.870 us; speedup vs baseline: 1.0345x; 1.0345x over previous
//
#include <hip/hip_runtime.h>
#include <hip/hip_bf16.h>
#include <stdint.h>

// Problem constants: b=2, s=2048, d=1024, H=16, DH=64, inner=1024
// External tensors FP32; internal bf16 MFMA.
#define NH     16
#define DHEAD  64
#define SEQ    2048
#define DMODEL 1024
#define NBATCH 2
#define INNER  1024
#define QKVN   3072
#define ROWS   4096      // NBATCH*SEQ
#define ATT_QB 64        // q rows per block (2 q-halves x 2 kv-halves, 4 waves)
#define ATT_KB 64        // kv rows per iteration

typedef __attribute__((ext_vector_type(8))) __bf16 bf16x8;
typedef __attribute__((ext_vector_type(4))) float floatx4;
typedef __attribute__((ext_vector_type(16))) float floatx16;

__device__ __forceinline__ unsigned short f2bf(float f) {
    union { __bf16 b; unsigned short u; } c; c.b = (__bf16)f; return c.u;
}

__device__ __forceinline__ unsigned int pk2(float lo, float hi) {
    union { ushort2 s; unsigned int u; } c;
    c.s.x = f2bf(lo); c.s.y = f2bf(hi); return c.u;
}

__device__ __forceinline__ float fexp2(float x) {
#if __has_builtin(__builtin_amdgcn_exp2f)
    return __builtin_amdgcn_exp2f(x);
#else
    float r; asm("v_exp_f32 %0, %1" : "=v"(r) : "v"(x)); return r;
#endif
}

typedef __attribute__((address_space(1))) void gvoid;
typedef __attribute__((address_space(3))) void lvoid;
__device__ __forceinline__ void gl_lds16(const void* g, void* l) {
    __builtin_amdgcn_global_load_lds((gvoid*)g, (lvoid*)l, 16, 0, 0);
}

// ------- fused prep: 2 weight transposes (fp32->bf16) + layernorm ---------------
// z=0: wqkv [1024,3072] -> wqkvT (x<96); z=1: wout [1024,1024] -> woutT (x<32);
// z=2: layernorm row = y*128+x over all 4096 rows. One launch instead of two.
__global__ __launch_bounds__(256) void prep_kernel(
        const float* __restrict__ x,
        const float* __restrict__ gamma,
        const float* __restrict__ beta,
        unsigned short* __restrict__ xn,
        const float* __restrict__ wqkv, unsigned short* __restrict__ wqkvT,
        const float* __restrict__ wout, unsigned short* __restrict__ woutT) {
    __shared__ unsigned short tile[32][33];
    __shared__ float red[4][2];
    const int t = threadIdx.x;
    if (blockIdx.z == 2) {
        // ---- layernorm fp32 -> bf16 ----
        const int row = blockIdx.y * 128 + blockIdx.x;
        const size_t base = (size_t)row * DMODEL + t * 4;
        float4 v = *(const float4*)(x + base);
        float s  = v.x + v.y + v.z + v.w;
        float ss = v.x*v.x + v.y*v.y + v.z*v.z + v.w*v.w;
        for (int off = 32; off >= 1; off >>= 1) {
            s  += __shfl_xor(s,  off);
            ss += __shfl_xor(ss, off);
        }
        const int w = t >> 6, lane = t & 63;
        if (lane == 0) { red[w][0] = s; red[w][1] = ss; }
        __syncthreads();
        if (t == 0) {
            float S  = red[0][0] + red[1][0] + red[2][0] + red[3][0];
            float SS = red[0][1] + red[1][1] + red[2][1] + red[3][1];
            float mu  = S * (1.f / DMODEL);
            float var = SS * (1.f / DMODEL) - mu * mu;
            red[0][0] = mu; red[0][1] = rsqrtf(var + 1e-5f);
        }
        __syncthreads();
        const float mu = red[0][0], rstd = red[0][1];
        float4 g = *(const float4*)(gamma + t * 4);
        float4 bb = *(const float4*)(beta + t * 4);
        ushort4 o;
        o.x = f2bf((v.x - mu) * rstd * g.x + bb.x);
        o.y = f2bf((v.y - mu) * rstd * g.y + bb.y);
        o.z = f2bf((v.z - mu) * rstd * g.z + bb.z);
        o.w = f2bf((v.w - mu) * rstd * g.w + bb.w);
        *(ushort4*)(xn + base) = o;
        return;
    }
    // ---- transpose + fp32->bf16: out[c][r] = bf16(in[r][c]) ----
    const float* in; unsigned short* out; int rows, cols;
    if (blockIdx.z == 0) {
        if (blockIdx.x >= QKVN / 32) return;
        in = wqkv; out = wqkvT; rows = DMODEL; cols = QKVN;
    } else {
        if (blockIdx.x >= DMODEL / 32) return;
        in = wout; out = woutT; rows = INNER; cols = DMODEL;
    }
    const int bx = blockIdx.x * 32, by = blockIdx.y * 32;
    const int tx = t & 31, ty = t >> 5;
    for (int i = ty; i < 32; i += 8)
        tile[i][tx] = f2bf(in[(size_t)(by + i) * cols + bx + tx]);
    __syncthreads();
    for (int i = ty; i < 32; i += 8)
        out[(size_t)(bx + i) * rows + by + tx] = tile[tx][i];
}

// ------- QKV GEMM: 128x128 tile, BK=32, 3-buffer depth-2 prefetch (T4+T5) -------
// Counted-vmcnt pipeline (r12, proven -7us): raw s_barrier; each wave waits its
// OWN vmcnt(4) for the tile it is about to read BEFORE the barrier -- the newest
// prefetch (4 loads) stays in flight across it. Depth-2 into 3 rotating buffers.
// ds_read fragments issued FIRST after the barrier, stage(kk+2) after, T5
// setprio(1) around the MFMA cluster (null-measured r13, harmless).
// LDS = 48KB -> 3 blocks/CU; grid 768 = exactly 3/CU.
__global__ __launch_bounds__(256) void gemm_qkv(
        const unsigned short* __restrict__ A,    // xn [4096,1024]
        const unsigned short* __restrict__ Bt,   // wqkvT [3072,1024]
        unsigned short* __restrict__ qP,
        unsigned short* __restrict__ kP,
        unsigned short* __restrict__ vT) {
    const int K = DMODEL;
    __shared__ __align__(16) unsigned short smem[3 * 8192];  // 48KB: 3 x (A 4096 + B 4096)
    const int t = threadIdx.x;
    const int mBase = blockIdx.y * 128, nBase = blockIdx.x * 128;
    const int w = t >> 6, lane = t & 63, quad = lane >> 4, l16 = lane & 15;
    const int wm = (w >> 1) * 64, wn = (w & 1) * 64;
    const int srow = t >> 2, sch = t & 3;
    floatx4 acc[4][4];
    for (int mi = 0; mi < 4; mi++)
        for (int ni = 0; ni < 4; ni++) acc[mi][ni] = (floatx4)0.f;

    auto stage = [&](int k0, int bi) {      // 4 gl_lds16 per wave (A0,B0,A1,B1)
        unsigned short* sA = smem + bi * 8192;
        unsigned short* sB = sA + 4096;
        #pragma unroll
        for (int c = 0; c < 2; c++) {
            const int row = c * 64 + srow;
            const int gcol = (sch ^ ((row >> 1) & 3)) * 8;
            gl_lds16(&A[(size_t)(mBase + row) * K + k0 + gcol], &sA[(c * 256 + w * 64) * 8]);
            gl_lds16(&Bt[(size_t)(nBase + row) * K + k0 + gcol], &sB[(c * 256 + w * 64) * 8]);
        }
    };

    const int NK = K / 32;                  // 32
    stage(0, 0);
    stage(32, 1);
    for (int kk = 0; kk < NK; ++kk) {
        // own stage(kk) landed; newest prefetch (4 loads) stays in flight
        if (kk + 1 < NK) { asm volatile("s_waitcnt vmcnt(4)" ::: "memory"); }
        else             { asm volatile("s_waitcnt vmcnt(0)" ::: "memory"); }
        __builtin_amdgcn_sched_barrier(0);
        __builtin_amdgcn_s_barrier();
        const unsigned short* sA = smem + (kk % 3) * 8192;
        const unsigned short* sB = sA + 4096;
        bf16x8 af[4], bfv[4];
        #pragma unroll
        for (int mi = 0; mi < 4; mi++) {
            const int r = wm + mi * 16 + l16;
            af[mi] = *(const bf16x8*)&sA[r * 32 + (quad ^ ((r >> 1) & 3)) * 8];
        }
        #pragma unroll
        for (int ni = 0; ni < 4; ni++) {
            const int r = wn + ni * 16 + l16;
            bfv[ni] = *(const bf16x8*)&sB[r * 32 + (quad ^ ((r >> 1) & 3)) * 8];
        }
        if (kk + 2 < NK) stage((kk + 2) * 32, (kk + 2) % 3);
        __builtin_amdgcn_s_setprio(1);
        #pragma unroll
        for (int mi = 0; mi < 4; mi++)
            #pragma unroll
            for (int ni = 0; ni < 4; ni++)
                acc[mi][ni] = __builtin_amdgcn_mfma_f32_16x16x32_bf16(
                    af[mi], bfv[ni], acc[mi][ni], 0, 0, 0);
        __builtin_amdgcn_s_setprio(0);
    }
    __syncthreads();                        // all reads done before epilogue overlay
    const int reg = nBase >> 10;                  // block-uniform: 0=q 1=k 2=v
    if (reg == 2) {
        #pragma unroll
        for (int ni = 0; ni < 4; ni++) {
            const int col = nBase + wn + ni * 16 + l16;
            const int h = (col & 1023) >> 6, dh = col & 63;
            #pragma unroll
            for (int mi = 0; mi < 4; mi++) {
                const int row0 = mBase + wm + mi * 16 + quad * 4;
                const int b = row0 >> 11, s0 = row0 & 2047;
                ushort4 o;
                o.x = f2bf(acc[mi][ni][0]); o.y = f2bf(acc[mi][ni][1]);
                o.z = f2bf(acc[mi][ni][2]); o.w = f2bf(acc[mi][ni][3]);
                *(ushort4*)&vT[((size_t)(b * NH + h) * DHEAD + dh) * SEQ + s0] = o;
            }
        }
    } else {
        unsigned short* dst = (reg == 0) ? qP : kP;
        // fold DHEAD^-0.5 * log2(e) into q so attn softmax is a bare v_exp_f32
        const float scl = (reg == 0) ? 0.18033688011112042f : 1.f;
        const int hh = ((nBase + wn) & 1023) >> 6;     // wave-uniform head
        // 4 per-wave tb buffers (36.9KB) overlay the retired 48KB staging LDS.
        unsigned short* tb_ = smem + w * (64 * 72);
        #pragma unroll
        for (int mi = 0; mi < 4; mi++)
            #pragma unroll
            for (int ni = 0; ni < 4; ni++)
                #pragma unroll
                for (int i = 0; i < 4; i++)
                    tb_[(mi * 16 + quad * 4 + i) * 72 + ni * 16 + l16] =
                        f2bf(acc[mi][ni][i] * scl);
        asm volatile("s_waitcnt lgkmcnt(0)" ::: "memory");   // own-wave tb writes done
        const int row_g = mBase + wm + lane;
        const int b = row_g >> 11, sr = row_g & 2047;
        unsigned short* orow = dst + ((size_t)(b * NH + hh) * SEQ + sr) * DHEAD;
        #pragma unroll
        for (int c = 0; c < 8; c++)
            *(bf16x8*)&orow[c * 8] = *(const bf16x8*)&tb_[lane * 72 + c * 8];
    }
}

// ------- out GEMM: C = A*Bt^T + bias (fp32), 128x64, BK=32, 3-buffer T4+T5 -----
// (r13 best config, reverted from r14's 64x64 retile which regressed +5us:
// smaller tile halved per-wave MFMA per K-step against the same LDS/barrier
// overhead -- occupancy was not the binding constraint here.)
// Counted-vmcnt pipeline; 3 loads per wave per stage -> vmcnt(3).
// LDS = 36KB -> grid 512 = 2/CU.
__global__ __launch_bounds__(256) void gemm_out(
        const unsigned short* __restrict__ A,
        const unsigned short* __restrict__ Bt,
        float* __restrict__ C,
        const int M, const int N, const int K,
        const float* __restrict__ bias) {
    __shared__ __align__(16) unsigned short smem[3 * 6144];  // 36KB: 3 x (A 4096 + B 2048)
    const int t = threadIdx.x;
    const int mBase = blockIdx.y * 128, nBase = blockIdx.x * 64;
    const int w = t >> 6, lane = t & 63, quad = lane >> 4, l16 = lane & 15;
    const int wm = (w >> 1) * 64, wn = (w & 1) * 32;
    const int srow = t >> 2, sch = t & 3;
    floatx4 acc[4][2];
    for (int mi = 0; mi < 4; mi++)
        for (int ni = 0; ni < 2; ni++) acc[mi][ni] = (floatx4)0.f;

    auto stage = [&](int k0, int bi) {      // 3 gl_lds16 per wave (A0,A1,B)
        unsigned short* sA = smem + bi * 6144;
        unsigned short* sB = sA + 4096;
        #pragma unroll
        for (int c = 0; c < 2; c++) {
            const int row = c * 64 + srow;
            const int gcol = (sch ^ ((row >> 1) & 3)) * 8;
            gl_lds16(&A[(size_t)(mBase + row) * K + k0 + gcol], &sA[(c * 256 + w * 64) * 8]);
        }
        {
            const int gcol = (sch ^ ((srow >> 1) & 3)) * 8;
            gl_lds16(&Bt[(size_t)(nBase + srow) * K + k0 + gcol], &sB[(w * 64) * 8]);
        }
    };

    const int NK = K / 32;
    stage(0, 0);
    stage(32, 1);
    for (int kk = 0; kk < NK; ++kk) {
        if (kk + 1 < NK) { asm volatile("s_waitcnt vmcnt(3)" ::: "memory"); }
        else             { asm volatile("s_waitcnt vmcnt(0)" ::: "memory"); }
        __builtin_amdgcn_sched_barrier(0);
        __builtin_amdgcn_s_barrier();
        const unsigned short* sA = smem + (kk % 3) * 6144;
        const unsigned short* sB = sA + 4096;
        bf16x8 af[4], bfv[2];
        #pragma unroll
        for (int mi = 0; mi < 4; mi++) {
            const int r = wm + mi * 16 + l16;
            af[mi] = *(const bf16x8*)&sA[r * 32 + (quad ^ ((r >> 1) & 3)) * 8];
        }
        #pragma unroll
        for (int ni = 0; ni < 2; ni++) {
            const int r = wn + ni * 16 + l16;
            bfv[ni] = *(const bf16x8*)&sB[r * 32 + (quad ^ ((r >> 1) & 3)) * 8];
        }
        if (kk + 2 < NK) stage((kk + 2) * 32, (kk + 2) % 3);
        __builtin_amdgcn_s_setprio(1);
        #pragma unroll
        for (int mi = 0; mi < 4; mi++)
            #pragma unroll
            for (int ni = 0; ni < 2; ni++)
                acc[mi][ni] = __builtin_amdgcn_mfma_f32_16x16x32_bf16(
                    af[mi], bfv[ni], acc[mi][ni], 0, 0, 0);
        __builtin_amdgcn_s_setprio(0);
    }
    #pragma unroll
    for (int mi = 0; mi < 4; mi++)
        #pragma unroll
        for (int ni = 0; ni < 2; ni++) {
            const int col = nBase + wn + ni * 16 + l16;
            const float badd = bias ? bias[col] : 0.f;
            #pragma unroll
            for (int i = 0; i < 4; i++) {
                const int row = mBase + wm + mi * 16 + quad * 4 + i;
                C[(size_t)row * N + col] = acc[mi][ni][i] + badd;
            }
        }
}

// ------- flash attention: 32x32 MFMA + in-reg P + KV-split 4-wave blocks --------
// (round-6 kernel, converged at ~58us -- kept byte-identical)
__global__ __launch_bounds__(256, 4) void attn_kernel(
        const unsigned short* __restrict__ qP,
        const unsigned short* __restrict__ kP,
        const unsigned short* __restrict__ vT,
        unsigned short* __restrict__ aout) {   // [4096][1024] bf16
    __shared__ __align__(16) unsigned short sK[2][ATT_KB * 64];
    __shared__ __align__(16) unsigned short sV[2][ATT_KB * 64];
    const int t = threadIdx.x, w = t >> 6, lane = t & 63;
    const int l32 = lane & 31, half = lane >> 5;
    const int qh = w & 1, kh = w >> 1;
    const int bid = blockIdx.x;                  // grid is 1024, 1-D
    const int xcd = bid & 7, slot = bid >> 3;    // 128 slots per XCD
    const int bh = xcd * 4 + (slot >> 5);        // 4 bh per XCD
    const int qb = slot & 31;
    const int b = bh >> 4, h = bh & 15;
    const int qbase = qb * ATT_QB + qh * 32;

    bf16x8 qf[4];
    #pragma unroll
    for (int kd = 0; kd < 4; kd++)
        qf[kd] = *(const bf16x8*)&qP[
            ((size_t)bh * SEQ + qbase + l32) * DHEAD + kd * 16 + half * 8];

    floatx16 oac[2];
    oac[0] = (floatx16)0.f; oac[1] = (floatx16)0.f;
    float lS = 0.f;

    const unsigned short* kb = kP + (size_t)bh * SEQ * DHEAD;
    const unsigned short* vb = vT + (size_t)bh * DHEAD * SEQ;
    const int r8 = lane >> 3, sw8 = ((lane & 7) ^ r8) * 8;

    auto stage = [&](int it, int bi) {
        const int kv0 = it * ATT_KB;
        #pragma unroll
        for (int ii = 0; ii < 2; ii++) {
            const int row = w * 16 + ii * 8 + r8;   // local row (row&7==r8)
            gl_lds16(kb + (size_t)(kv0 + row) * DHEAD + sw8,
                     (void*)&sK[bi][(w * 16 + ii * 8) * 64]);
            gl_lds16(vb + (size_t)row * SEQ + kv0 + sw8,
                     (void*)&sV[bi][(w * 16 + ii * 8) * 64]);
        }
    };
    stage(0, 0);

    const int NIT = SEQ / ATT_KB;      // 32
    for (int it = 0; it < NIT; ++it) {
        __syncthreads();               // staging of tile `it` landed (all waves)
        const int bi = it & 1;
        if (it + 1 < NIT) stage(it + 1, bi ^ 1);   // writes buf^1: disjoint

        bf16x8 kf[4];
        #pragma unroll
        for (int kd = 0; kd < 4; kd++) {
            const int r = kh * 32 + l32;
            kf[kd] = *(const bf16x8*)&sK[bi][r * 64 + 8 * ((2 * kd + half) ^ (l32 & 7))];
        }

        floatx16 sv = (floatx16)0.f;
        __builtin_amdgcn_s_setprio(1);
        #pragma unroll
        for (int kd = 0; kd < 4; kd++)
            sv = __builtin_amdgcn_mfma_f32_32x32x16_bf16(kf[kd], qf[kd], sv, 0, 0, 0);
        __builtin_amdgcn_s_setprio(0);

        float p[16];
        #pragma unroll
        for (int i = 0; i < 16; i++) p[i] = fexp2(sv[i]);
        {
            float s = 0.f;
            #pragma unroll
            for (int i = 0; i < 16; i++) s += p[i];
            s += __shfl_xor(s, 32);    // partner half covers the other 16 rows
            lS += s;
        }

        bf16x8 pf[2];
        #pragma unroll
        for (int kd = 0; kd < 2; kd++) {
            const int base = kd * 8;
            unsigned int c01 = pk2(p[base + 0], p[base + 1]);
            unsigned int c23 = pk2(p[base + 2], p[base + 3]);
            unsigned int c45 = pk2(p[base + 4], p[base + 5]);
            unsigned int c67 = pk2(p[base + 6], p[base + 7]);
            asm("v_permlane32_swap_b32 %0, %1" : "+v"(c01), "+v"(c45));
            asm("v_permlane32_swap_b32 %0, %1" : "+v"(c23), "+v"(c67));
            union { unsigned int u[4]; bf16x8 v; } fr;
            fr.u[0] = c01; fr.u[1] = c23; fr.u[2] = c45; fr.u[3] = c67;
            pf[kd] = fr.v;
        }

        __builtin_amdgcn_s_setprio(1);
        #pragma unroll
        for (int dt = 0; dt < 2; dt++)
            #pragma unroll
            for (int kd = 0; kd < 2; kd++) {
                const int r = dt * 32 + l32;
                bf16x8 vf = *(const bf16x8*)&sV[bi][
                    r * 64 + 8 * ((kh * 4 + kd * 2 + half) ^ (l32 & 7))];
                oac[dt] = __builtin_amdgcn_mfma_f32_32x32x16_bf16(vf, pf[kd], oac[dt], 0, 0, 0);
            }
        __builtin_amdgcn_s_setprio(0);
    }

    __syncthreads();
    float* redO = (float*)&sK[0][0];   // [2 qh][64 lanes][32 f32] = 16KB (== sK)
    float* redL = (float*)&sV[0][0];   // [2 qh][32 q] f32
    if (kh == 1) {
        #pragma unroll
        for (int dt = 0; dt < 2; dt++)
            #pragma unroll
            for (int g = 0; g < 4; g++) {
                const int c = dt * 4 + g;
                float4 o4;
                o4.x = oac[dt][g * 4 + 0]; o4.y = oac[dt][g * 4 + 1];
                o4.z = oac[dt][g * 4 + 2]; o4.w = oac[dt][g * 4 + 3];
                *(float4*)&redO[((size_t)qh * 64 + lane) * 32 + 4 * (c ^ (lane & 7))] = o4;
            }
        if (half == 0) redL[qh * 32 + l32] = lS;
    }
    __syncthreads();
    if (kh == 0) {
        #pragma unroll
        for (int dt = 0; dt < 2; dt++)
            #pragma unroll
            for (int g = 0; g < 4; g++) {
                const int c = dt * 4 + g;
                float4 o4 = *(const float4*)&redO[
                    ((size_t)qh * 64 + lane) * 32 + 4 * (c ^ (lane & 7))];
                oac[dt][g * 4 + 0] += o4.x; oac[dt][g * 4 + 1] += o4.y;
                oac[dt][g * 4 + 2] += o4.z; oac[dt][g * 4 + 3] += o4.w;
            }
        lS += redL[qh * 32 + l32];
        const float rl = 1.f / lS;
        unsigned short* orow = aout + ((size_t)(b * SEQ + qbase + l32)) * INNER + h * DHEAD;
        #pragma unroll
        for (int dt = 0; dt < 2; dt++)
            #pragma unroll
            for (int g = 0; g < 4; g++) {
                ushort4 o;
                o.x = f2bf(oac[dt][g * 4 + 0] * rl);
                o.y = f2bf(oac[dt][g * 4 + 1] * rl);
                o.z = f2bf(oac[dt][g * 4 + 2] * rl);
                o.w = f2bf(oac[dt][g * 4 + 3] * rl);
                *(ushort4*)&orow[dt * 32 + g * 8 + half * 4] = o;
            }
    }
}

extern "C" void kernel_launch(void* const* d_in, const int* in_sizes, int n_in,
                              void* d_out, int out_size, void* d_ws, size_t ws_size,
                              hipStream_t stream) {
    const float* x     = (const float*)d_in[0];
    const float* gamma = (const float*)d_in[1];
    const float* beta  = (const float*)d_in[2];
    const float* wqkv  = (const float*)d_in[3];
    const float* wout  = (const float*)d_in[4];
    const float* bout  = (const float*)d_in[5];
    float* out = (float*)d_out;

    unsigned short* ws     = (unsigned short*)d_ws;
    unsigned short* xn     = ws;                                  // 4096x1024
    unsigned short* wqkvT  = xn     + (size_t)ROWS * DMODEL;      // 3072x1024
    unsigned short* qPb    = wqkvT  + (size_t)QKVN * DMODEL;      // 32x2048x64
    unsigned short* kPb    = qPb    + (size_t)NBATCH * NH * SEQ * DHEAD;
    unsigned short* vTb    = kPb    + (size_t)NBATCH * NH * SEQ * DHEAD;
    unsigned short* attnO  = vTb    + (size_t)NBATCH * NH * SEQ * DHEAD; // 4096x1024
    unsigned short* woutT  = attnO  + (size_t)ROWS * INNER;       // 1024x1024

    // z=0: wqkv transpose (x<96); z=1: wout transpose (x<32); z=2: LN (128x32=4096 rows)
    prep_kernel<<<dim3(128, 32, 3), 256, 0, stream>>>(
        x, gamma, beta, xn, wqkv, wqkvT, wout, woutT);
    gemm_qkv<<<dim3(QKVN / 128, ROWS / 128), 256, 0, stream>>>(xn, wqkvT, qPb, kPb, vTb);
    attn_kernel<<<dim3((SEQ / ATT_QB) * NBATCH * NH), 256, 0, stream>>>(
        qPb, kPb, vTb, attnO);
    gemm_out<<<dim3(DMODEL / 64, ROWS / 128), 256, 0, stream>>>(
        attnO, woutT, out, ROWS, DMODEL, INNER, bout);
}

// Round 16
// 188.379 us; speedup vs baseline: 1.0592x; 1.0238x over previous
//
#include <hip/hip_runtime.h>
#include <hip/hip_bf16.h>
#include <stdint.h>

// Problem constants: b=2, s=2048, d=1024, H=16, DH=64, inner=1024
// External tensors FP32; internal bf16 MFMA.
#define NH     16
#define DHEAD  64
#define SEQ    2048
#define DMODEL 1024
#define NBATCH 2
#define INNER  1024
#define QKVN   3072
#define ROWS   4096      // NBATCH*SEQ
#define ATT_QB 128       // q rows per block (4 q-subtiles x 2 kv-halves, 8 waves)
#define ATT_KB 64        // kv rows per iteration

typedef __attribute__((ext_vector_type(8))) __bf16 bf16x8;
typedef __attribute__((ext_vector_type(4))) float floatx4;
typedef __attribute__((ext_vector_type(16))) float floatx16;

__device__ __forceinline__ unsigned short f2bf(float f) {
    union { __bf16 b; unsigned short u; } c; c.b = (__bf16)f; return c.u;
}

__device__ __forceinline__ unsigned int pk2(float lo, float hi) {
    union { ushort2 s; unsigned int u; } c;
    c.s.x = f2bf(lo); c.s.y = f2bf(hi); return c.u;
}

__device__ __forceinline__ float fexp2(float x) {
#if __has_builtin(__builtin_amdgcn_exp2f)
    return __builtin_amdgcn_exp2f(x);
#else
    float r; asm("v_exp_f32 %0, %1" : "=v"(r) : "v"(x)); return r;
#endif
}

typedef __attribute__((address_space(1))) void gvoid;
typedef __attribute__((address_space(3))) void lvoid;
__device__ __forceinline__ void gl_lds16(const void* g, void* l) {
    __builtin_amdgcn_global_load_lds((gvoid*)g, (lvoid*)l, 16, 0, 0);
}

// ------- fused prep: 2 weight transposes (fp32->bf16) + layernorm ---------------
// z=0: wqkv [1024,3072] -> wqkvT (x<96); z=1: wout [1024,1024] -> woutT (x<32);
// z=2: layernorm row = y*128+x over all 4096 rows. One launch instead of two.
__global__ __launch_bounds__(256) void prep_kernel(
        const float* __restrict__ x,
        const float* __restrict__ gamma,
        const float* __restrict__ beta,
        unsigned short* __restrict__ xn,
        const float* __restrict__ wqkv, unsigned short* __restrict__ wqkvT,
        const float* __restrict__ wout, unsigned short* __restrict__ woutT) {
    __shared__ unsigned short tile[32][33];
    __shared__ float red[4][2];
    const int t = threadIdx.x;
    if (blockIdx.z == 2) {
        // ---- layernorm fp32 -> bf16 ----
        const int row = blockIdx.y * 128 + blockIdx.x;
        const size_t base = (size_t)row * DMODEL + t * 4;
        float4 v = *(const float4*)(x + base);
        float s  = v.x + v.y + v.z + v.w;
        float ss = v.x*v.x + v.y*v.y + v.z*v.z + v.w*v.w;
        for (int off = 32; off >= 1; off >>= 1) {
            s  += __shfl_xor(s,  off);
            ss += __shfl_xor(ss, off);
        }
        const int w = t >> 6, lane = t & 63;
        if (lane == 0) { red[w][0] = s; red[w][1] = ss; }
        __syncthreads();
        if (t == 0) {
            float S  = red[0][0] + red[1][0] + red[2][0] + red[3][0];
            float SS = red[0][1] + red[1][1] + red[2][1] + red[3][1];
            float mu  = S * (1.f / DMODEL);
            float var = SS * (1.f / DMODEL) - mu * mu;
            red[0][0] = mu; red[0][1] = rsqrtf(var + 1e-5f);
        }
        __syncthreads();
        const float mu = red[0][0], rstd = red[0][1];
        float4 g = *(const float4*)(gamma + t * 4);
        float4 bb = *(const float4*)(beta + t * 4);
        ushort4 o;
        o.x = f2bf((v.x - mu) * rstd * g.x + bb.x);
        o.y = f2bf((v.y - mu) * rstd * g.y + bb.y);
        o.z = f2bf((v.z - mu) * rstd * g.z + bb.z);
        o.w = f2bf((v.w - mu) * rstd * g.w + bb.w);
        *(ushort4*)(xn + base) = o;
        return;
    }
    // ---- transpose + fp32->bf16: out[c][r] = bf16(in[r][c]) ----
    const float* in; unsigned short* out; int rows, cols;
    if (blockIdx.z == 0) {
        if (blockIdx.x >= QKVN / 32) return;
        in = wqkv; out = wqkvT; rows = DMODEL; cols = QKVN;
    } else {
        if (blockIdx.x >= DMODEL / 32) return;
        in = wout; out = woutT; rows = INNER; cols = DMODEL;
    }
    const int bx = blockIdx.x * 32, by = blockIdx.y * 32;
    const int tx = t & 31, ty = t >> 5;
    for (int i = ty; i < 32; i += 8)
        tile[i][tx] = f2bf(in[(size_t)(by + i) * cols + bx + tx]);
    __syncthreads();
    for (int i = ty; i < 32; i += 8)
        out[(size_t)(bx + i) * rows + by + tx] = tile[tx][i];
}

// ------- QKV GEMM: 128x128 tile, BK=32, 3-buffer depth-2 prefetch (T4+T5) -------
// Counted-vmcnt pipeline (r12, proven -7us): raw s_barrier; each wave waits its
// OWN vmcnt(4) for the tile it is about to read BEFORE the barrier -- the newest
// prefetch (4 loads) stays in flight across it. Depth-2 into 3 rotating buffers.
// LDS = 48KB -> 3 blocks/CU; grid 768 = exactly 3/CU.
__global__ __launch_bounds__(256) void gemm_qkv(
        const unsigned short* __restrict__ A,    // xn [4096,1024]
        const unsigned short* __restrict__ Bt,   // wqkvT [3072,1024]
        unsigned short* __restrict__ qP,
        unsigned short* __restrict__ kP,
        unsigned short* __restrict__ vT) {
    const int K = DMODEL;
    __shared__ __align__(16) unsigned short smem[3 * 8192];  // 48KB: 3 x (A 4096 + B 4096)
    const int t = threadIdx.x;
    const int mBase = blockIdx.y * 128, nBase = blockIdx.x * 128;
    const int w = t >> 6, lane = t & 63, quad = lane >> 4, l16 = lane & 15;
    const int wm = (w >> 1) * 64, wn = (w & 1) * 64;
    const int srow = t >> 2, sch = t & 3;
    floatx4 acc[4][4];
    for (int mi = 0; mi < 4; mi++)
        for (int ni = 0; ni < 4; ni++) acc[mi][ni] = (floatx4)0.f;

    auto stage = [&](int k0, int bi) {      // 4 gl_lds16 per wave (A0,B0,A1,B1)
        unsigned short* sA = smem + bi * 8192;
        unsigned short* sB = sA + 4096;
        #pragma unroll
        for (int c = 0; c < 2; c++) {
            const int row = c * 64 + srow;
            const int gcol = (sch ^ ((row >> 1) & 3)) * 8;
            gl_lds16(&A[(size_t)(mBase + row) * K + k0 + gcol], &sA[(c * 256 + w * 64) * 8]);
            gl_lds16(&Bt[(size_t)(nBase + row) * K + k0 + gcol], &sB[(c * 256 + w * 64) * 8]);
        }
    };

    const int NK = K / 32;                  // 32
    stage(0, 0);
    stage(32, 1);
    for (int kk = 0; kk < NK; ++kk) {
        // own stage(kk) landed; newest prefetch (4 loads) stays in flight
        if (kk + 1 < NK) { asm volatile("s_waitcnt vmcnt(4)" ::: "memory"); }
        else             { asm volatile("s_waitcnt vmcnt(0)" ::: "memory"); }
        __builtin_amdgcn_sched_barrier(0);
        __builtin_amdgcn_s_barrier();
        const unsigned short* sA = smem + (kk % 3) * 8192;
        const unsigned short* sB = sA + 4096;
        bf16x8 af[4], bfv[4];
        #pragma unroll
        for (int mi = 0; mi < 4; mi++) {
            const int r = wm + mi * 16 + l16;
            af[mi] = *(const bf16x8*)&sA[r * 32 + (quad ^ ((r >> 1) & 3)) * 8];
        }
        #pragma unroll
        for (int ni = 0; ni < 4; ni++) {
            const int r = wn + ni * 16 + l16;
            bfv[ni] = *(const bf16x8*)&sB[r * 32 + (quad ^ ((r >> 1) & 3)) * 8];
        }
        if (kk + 2 < NK) stage((kk + 2) * 32, (kk + 2) % 3);
        __builtin_amdgcn_s_setprio(1);
        #pragma unroll
        for (int mi = 0; mi < 4; mi++)
            #pragma unroll
            for (int ni = 0; ni < 4; ni++)
                acc[mi][ni] = __builtin_amdgcn_mfma_f32_16x16x32_bf16(
                    af[mi], bfv[ni], acc[mi][ni], 0, 0, 0);
        __builtin_amdgcn_s_setprio(0);
    }
    __syncthreads();                        // all reads done before epilogue overlay
    const int reg = nBase >> 10;                  // block-uniform: 0=q 1=k 2=v
    if (reg == 2) {
        #pragma unroll
        for (int ni = 0; ni < 4; ni++) {
            const int col = nBase + wn + ni * 16 + l16;
            const int h = (col & 1023) >> 6, dh = col & 63;
            #pragma unroll
            for (int mi = 0; mi < 4; mi++) {
                const int row0 = mBase + wm + mi * 16 + quad * 4;
                const int b = row0 >> 11, s0 = row0 & 2047;
                ushort4 o;
                o.x = f2bf(acc[mi][ni][0]); o.y = f2bf(acc[mi][ni][1]);
                o.z = f2bf(acc[mi][ni][2]); o.w = f2bf(acc[mi][ni][3]);
                *(ushort4*)&vT[((size_t)(b * NH + h) * DHEAD + dh) * SEQ + s0] = o;
            }
        }
    } else {
        unsigned short* dst = (reg == 0) ? qP : kP;
        // fold DHEAD^-0.5 * log2(e) into q so attn softmax is a bare v_exp_f32
        const float scl = (reg == 0) ? 0.18033688011112042f : 1.f;
        const int hh = ((nBase + wn) & 1023) >> 6;     // wave-uniform head
        // 4 per-wave tb buffers (36.9KB) overlay the retired 48KB staging LDS.
        unsigned short* tb_ = smem + w * (64 * 72);
        #pragma unroll
        for (int mi = 0; mi < 4; mi++)
            #pragma unroll
            for (int ni = 0; ni < 4; ni++)
                #pragma unroll
                for (int i = 0; i < 4; i++)
                    tb_[(mi * 16 + quad * 4 + i) * 72 + ni * 16 + l16] =
                        f2bf(acc[mi][ni][i] * scl);
        asm volatile("s_waitcnt lgkmcnt(0)" ::: "memory");   // own-wave tb writes done
        const int row_g = mBase + wm + lane;
        const int b = row_g >> 11, sr = row_g & 2047;
        unsigned short* orow = dst + ((size_t)(b * NH + hh) * SEQ + sr) * DHEAD;
        #pragma unroll
        for (int c = 0; c < 8; c++)
            *(bf16x8*)&orow[c * 8] = *(const bf16x8*)&tb_[lane * 72 + c * 8];
    }
}

// ------- out GEMM: C = A*Bt^T + bias (fp32), 128x64, BK=32, 3-buffer T4+T5 -----
// (r13/r15 best config.) Counted-vmcnt pipeline; vmcnt(3). LDS = 36KB, grid 512.
__global__ __launch_bounds__(256) void gemm_out(
        const unsigned short* __restrict__ A,
        const unsigned short* __restrict__ Bt,
        float* __restrict__ C,
        const int M, const int N, const int K,
        const float* __restrict__ bias) {
    __shared__ __align__(16) unsigned short smem[3 * 6144];  // 36KB: 3 x (A 4096 + B 2048)
    const int t = threadIdx.x;
    const int mBase = blockIdx.y * 128, nBase = blockIdx.x * 64;
    const int w = t >> 6, lane = t & 63, quad = lane >> 4, l16 = lane & 15;
    const int wm = (w >> 1) * 64, wn = (w & 1) * 32;
    const int srow = t >> 2, sch = t & 3;
    floatx4 acc[4][2];
    for (int mi = 0; mi < 4; mi++)
        for (int ni = 0; ni < 2; ni++) acc[mi][ni] = (floatx4)0.f;

    auto stage = [&](int k0, int bi) {      // 3 gl_lds16 per wave (A0,A1,B)
        unsigned short* sA = smem + bi * 6144;
        unsigned short* sB = sA + 4096;
        #pragma unroll
        for (int c = 0; c < 2; c++) {
            const int row = c * 64 + srow;
            const int gcol = (sch ^ ((row >> 1) & 3)) * 8;
            gl_lds16(&A[(size_t)(mBase + row) * K + k0 + gcol], &sA[(c * 256 + w * 64) * 8]);
        }
        {
            const int gcol = (sch ^ ((srow >> 1) & 3)) * 8;
            gl_lds16(&Bt[(size_t)(nBase + srow) * K + k0 + gcol], &sB[(w * 64) * 8]);
        }
    };

    const int NK = K / 32;
    stage(0, 0);
    stage(32, 1);
    for (int kk = 0; kk < NK; ++kk) {
        if (kk + 1 < NK) { asm volatile("s_waitcnt vmcnt(3)" ::: "memory"); }
        else             { asm volatile("s_waitcnt vmcnt(0)" ::: "memory"); }
        __builtin_amdgcn_sched_barrier(0);
        __builtin_amdgcn_s_barrier();
        const unsigned short* sA = smem + (kk % 3) * 6144;
        const unsigned short* sB = sA + 4096;
        bf16x8 af[4], bfv[2];
        #pragma unroll
        for (int mi = 0; mi < 4; mi++) {
            const int r = wm + mi * 16 + l16;
            af[mi] = *(const bf16x8*)&sA[r * 32 + (quad ^ ((r >> 1) & 3)) * 8];
        }
        #pragma unroll
        for (int ni = 0; ni < 2; ni++) {
            const int r = wn + ni * 16 + l16;
            bfv[ni] = *(const bf16x8*)&sB[r * 32 + (quad ^ ((r >> 1) & 3)) * 8];
        }
        if (kk + 2 < NK) stage((kk + 2) * 32, (kk + 2) % 3);
        __builtin_amdgcn_s_setprio(1);
        #pragma unroll
        for (int mi = 0; mi < 4; mi++)
            #pragma unroll
            for (int ni = 0; ni < 2; ni++)
                acc[mi][ni] = __builtin_amdgcn_mfma_f32_16x16x32_bf16(
                    af[mi], bfv[ni], acc[mi][ni], 0, 0, 0);
        __builtin_amdgcn_s_setprio(0);
    }
    #pragma unroll
    for (int mi = 0; mi < 4; mi++)
        #pragma unroll
        for (int ni = 0; ni < 2; ni++) {
            const int col = nBase + wn + ni * 16 + l16;
            const float badd = bias ? bias[col] : 0.f;
            #pragma unroll
            for (int i = 0; i < 4; i++) {
                const int row = mBase + wm + mi * 16 + quad * 4 + i;
                C[(size_t)row * N + col] = acc[mi][ni][i] + badd;
            }
        }
}

// ------- flash attention: 32x32 MFMA + in-reg P, 8-wave 128-q blocks ------------
// r16: same per-wave inner loop as the converged r6 kernel, but the block now
// covers 128 q rows (4 q-subtiles x 2 kv-halves, 8 waves). Each KV tile staged
// once serves 2x the q rows -> K/V DMA, L2 reads, and barrier-events per q-row
// all halve. Grid 512 = 2 blocks/CU x 8 waves = 16 waves/CU (same TLP as r6).
// LDS: sK/sV dbuf 32KB; combine scratch redO (4x64x32 f32 = 32KB) overlays it.
// Staging invariant preserved: each wave stages 8 rows (row&7 == lane>>3).
__global__ __launch_bounds__(512, 4) void attn_kernel(
        const unsigned short* __restrict__ qP,
        const unsigned short* __restrict__ kP,
        const unsigned short* __restrict__ vT,
        unsigned short* __restrict__ aout) {   // [4096][1024] bf16
    __shared__ __align__(16) unsigned short kvs[16384];  // sK[2][4096] ++ sV[2][4096]
    __shared__ float redL[4][32];
    unsigned short* sK0 = kvs;            // sK[bi] = kvs + bi*4096
    unsigned short* sV0 = kvs + 8192;     // sV[bi] = kvs + 8192 + bi*4096
    const int t = threadIdx.x, w = t >> 6, lane = t & 63;
    const int l32 = lane & 31, half = lane >> 5;
    const int qq = w & 3, kh = w >> 2;
    // XCD-aware remap: grid 512 = 8 XCD x 64 slots; 4 bh x 16 qb per XCD.
    const int bid = blockIdx.x;
    const int xcd = bid & 7, slot = bid >> 3;
    const int bh = xcd * 4 + (slot >> 4);
    const int qb = slot & 15;
    const int b = bh >> 4, h = bh & 15;
    const int qbase = qb * ATT_QB + qq * 32;

    bf16x8 qf[4];
    #pragma unroll
    for (int kd = 0; kd < 4; kd++)
        qf[kd] = *(const bf16x8*)&qP[
            ((size_t)bh * SEQ + qbase + l32) * DHEAD + kd * 16 + half * 8];

    floatx16 oac[2];
    oac[0] = (floatx16)0.f; oac[1] = (floatx16)0.f;
    float lS = 0.f;

    const unsigned short* kb = kP + (size_t)bh * SEQ * DHEAD;
    const unsigned short* vb = vT + (size_t)bh * DHEAD * SEQ;
    const int r8 = lane >> 3, sw8 = ((lane & 7) ^ r8) * 8;

    auto stage = [&](int it, int bi) {
        const int kv0 = it * ATT_KB;
        const int row = w * 8 + r8;          // 8 waves x 8 rows = 64 (row&7==r8)
        gl_lds16(kb + (size_t)(kv0 + row) * DHEAD + sw8,
                 (void*)&sK0[bi * 4096 + (w * 8) * 64]);
        gl_lds16(vb + (size_t)row * SEQ + kv0 + sw8,
                 (void*)&sV0[bi * 4096 + (w * 8) * 64]);
    };
    stage(0, 0);

    const int NIT = SEQ / ATT_KB;      // 32
    for (int it = 0; it < NIT; ++it) {
        __syncthreads();               // staging of tile `it` landed (all waves)
        const int bi = it & 1;
        if (it + 1 < NIT) stage(it + 1, bi ^ 1);   // writes buf^1: disjoint

        bf16x8 kf[4];
        #pragma unroll
        for (int kd = 0; kd < 4; kd++) {
            const int r = kh * 32 + l32;
            kf[kd] = *(const bf16x8*)&sK0[bi * 4096 + r * 64 +
                                          8 * ((2 * kd + half) ^ (l32 & 7))];
        }

        floatx16 sv = (floatx16)0.f;
        __builtin_amdgcn_s_setprio(1);
        #pragma unroll
        for (int kd = 0; kd < 4; kd++)
            sv = __builtin_amdgcn_mfma_f32_32x32x16_bf16(kf[kd], qf[kd], sv, 0, 0, 0);
        __builtin_amdgcn_s_setprio(0);

        float p[16];
        #pragma unroll
        for (int i = 0; i < 16; i++) p[i] = fexp2(sv[i]);
        {
            float s = 0.f;
            #pragma unroll
            for (int i = 0; i < 16; i++) s += p[i];
            s += __shfl_xor(s, 32);    // partner half covers the other 16 rows
            lS += s;
        }

        bf16x8 pf[2];
        #pragma unroll
        for (int kd = 0; kd < 2; kd++) {
            const int base = kd * 8;
            unsigned int c01 = pk2(p[base + 0], p[base + 1]);
            unsigned int c23 = pk2(p[base + 2], p[base + 3]);
            unsigned int c45 = pk2(p[base + 4], p[base + 5]);
            unsigned int c67 = pk2(p[base + 6], p[base + 7]);
            asm("v_permlane32_swap_b32 %0, %1" : "+v"(c01), "+v"(c45));
            asm("v_permlane32_swap_b32 %0, %1" : "+v"(c23), "+v"(c67));
            union { unsigned int u[4]; bf16x8 v; } fr;
            fr.u[0] = c01; fr.u[1] = c23; fr.u[2] = c45; fr.u[3] = c67;
            pf[kd] = fr.v;
        }

        __builtin_amdgcn_s_setprio(1);
        #pragma unroll
        for (int dt = 0; dt < 2; dt++)
            #pragma unroll
            for (int kd = 0; kd < 2; kd++) {
                const int r = dt * 32 + l32;
                bf16x8 vf = *(const bf16x8*)&sV0[bi * 4096 + r * 64 +
                    8 * ((kh * 4 + kd * 2 + half) ^ (l32 & 7))];
                oac[dt] = __builtin_amdgcn_mfma_f32_32x32x16_bf16(vf, pf[kd], oac[dt], 0, 0, 0);
            }
        __builtin_amdgcn_s_setprio(0);
    }

    // ---- cross-wave combine over kv-halves (redO overlays retired sK/sV) ----
    __syncthreads();
    float* redO = (float*)kvs;   // [4 qq][64 lanes][32 f32] = 32KB (== kvs)
    if (kh == 1) {
        #pragma unroll
        for (int dt = 0; dt < 2; dt++)
            #pragma unroll
            for (int g = 0; g < 4; g++) {
                const int c = dt * 4 + g;
                float4 o4;
                o4.x = oac[dt][g * 4 + 0]; o4.y = oac[dt][g * 4 + 1];
                o4.z = oac[dt][g * 4 + 2]; o4.w = oac[dt][g * 4 + 3];
                *(float4*)&redO[((size_t)qq * 64 + lane) * 32 + 4 * (c ^ (lane & 7))] = o4;
            }
        if (half == 0) redL[qq][l32] = lS;
    }
    __syncthreads();
    if (kh == 0) {
        #pragma unroll
        for (int dt = 0; dt < 2; dt++)
            #pragma unroll
            for (int g = 0; g < 4; g++) {
                const int c = dt * 4 + g;
                float4 o4 = *(const float4*)&redO[
                    ((size_t)qq * 64 + lane) * 32 + 4 * (c ^ (lane & 7))];
                oac[dt][g * 4 + 0] += o4.x; oac[dt][g * 4 + 1] += o4.y;
                oac[dt][g * 4 + 2] += o4.z; oac[dt][g * 4 + 3] += o4.w;
            }
        lS += redL[qq][l32];
        const float rl = 1.f / lS;
        unsigned short* orow = aout + ((size_t)(b * SEQ + qbase + l32)) * INNER + h * DHEAD;
        #pragma unroll
        for (int dt = 0; dt < 2; dt++)
            #pragma unroll
            for (int g = 0; g < 4; g++) {
                ushort4 o;
                o.x = f2bf(oac[dt][g * 4 + 0] * rl);
                o.y = f2bf(oac[dt][g * 4 + 1] * rl);
                o.z = f2bf(oac[dt][g * 4 + 2] * rl);
                o.w = f2bf(oac[dt][g * 4 + 3] * rl);
                *(ushort4*)&orow[dt * 32 + g * 8 + half * 4] = o;
            }
    }
}

extern "C" void kernel_launch(void* const* d_in, const int* in_sizes, int n_in,
                              void* d_out, int out_size, void* d_ws, size_t ws_size,
                              hipStream_t stream) {
    const float* x     = (const float*)d_in[0];
    const float* gamma = (const float*)d_in[1];
    const float* beta  = (const float*)d_in[2];
    const float* wqkv  = (const float*)d_in[3];
    const float* wout  = (const float*)d_in[4];
    const float* bout  = (const float*)d_in[5];
    float* out = (float*)d_out;

    unsigned short* ws     = (unsigned short*)d_ws;
    unsigned short* xn     = ws;                                  // 4096x1024
    unsigned short* wqkvT  = xn     + (size_t)ROWS * DMODEL;      // 3072x1024
    unsigned short* qPb    = wqkvT  + (size_t)QKVN * DMODEL;      // 32x2048x64
    unsigned short* kPb    = qPb    + (size_t)NBATCH * NH * SEQ * DHEAD;
    unsigned short* vTb    = kPb    + (size_t)NBATCH * NH * SEQ * DHEAD;
    unsigned short* attnO  = vTb    + (size_t)NBATCH * NH * SEQ * DHEAD; // 4096x1024
    unsigned short* woutT  = attnO  + (size_t)ROWS * INNER;       // 1024x1024

    // z=0: wqkv transpose (x<96); z=1: wout transpose (x<32); z=2: LN (128x32=4096 rows)
    prep_kernel<<<dim3(128, 32, 3), 256, 0, stream>>>(
        x, gamma, beta, xn, wqkv, wqkvT, wout, woutT);
    gemm_qkv<<<dim3(QKVN / 128, ROWS / 128), 256, 0, stream>>>(xn, wqkvT, qPb, kPb, vTb);
    attn_kernel<<<dim3((SEQ / ATT_QB) * NBATCH * NH), 512, 0, stream>>>(
        qPb, kPb, vTb, attnO);
    gemm_out<<<dim3(DMODEL / 64, ROWS / 128), 256, 0, stream>>>(
        attnO, woutT, out, ROWS, DMODEL, INNER, bout);
}

// Round 17
// 187.335 us; speedup vs baseline: 1.0651x; 1.0056x over previous
//
#include <hip/hip_runtime.h>
#include <hip/hip_bf16.h>
#include <stdint.h>

// Problem constants: b=2, s=2048, d=1024, H=16, DH=64, inner=1024
// External tensors FP32; internal bf16 MFMA.
#define NH     16
#define DHEAD  64
#define SEQ    2048
#define DMODEL 1024
#define NBATCH 2
#define INNER  1024
#define QKVN   3072
#define ROWS   4096      // NBATCH*SEQ
#define ATT_QB 128       // q rows per block (4 q-subtiles x 2 kv-halves, 8 waves)
#define ATT_KB 128       // kv rows per iteration (2 sub-tiles of 32 per kv-half)

typedef __attribute__((ext_vector_type(8))) __bf16 bf16x8;
typedef __attribute__((ext_vector_type(4))) float floatx4;
typedef __attribute__((ext_vector_type(16))) float floatx16;

__device__ __forceinline__ unsigned short f2bf(float f) {
    union { __bf16 b; unsigned short u; } c; c.b = (__bf16)f; return c.u;
}

__device__ __forceinline__ unsigned int pk2(float lo, float hi) {
    union { ushort2 s; unsigned int u; } c;
    c.s.x = f2bf(lo); c.s.y = f2bf(hi); return c.u;
}

__device__ __forceinline__ float fexp2(float x) {
#if __has_builtin(__builtin_amdgcn_exp2f)
    return __builtin_amdgcn_exp2f(x);
#else
    float r; asm("v_exp_f32 %0, %1" : "=v"(r) : "v"(x)); return r;
#endif
}

typedef __attribute__((address_space(1))) void gvoid;
typedef __attribute__((address_space(3))) void lvoid;
__device__ __forceinline__ void gl_lds16(const void* g, void* l) {
    __builtin_amdgcn_global_load_lds((gvoid*)g, (lvoid*)l, 16, 0, 0);
}

// ------- fused prep: 2 weight transposes (fp32->bf16) + layernorm ---------------
// z=0: wqkv [1024,3072] -> wqkvT (x<96); z=1: wout [1024,1024] -> woutT (x<32);
// z=2: layernorm row = y*128+x over all 4096 rows. One launch instead of two.
__global__ __launch_bounds__(256) void prep_kernel(
        const float* __restrict__ x,
        const float* __restrict__ gamma,
        const float* __restrict__ beta,
        unsigned short* __restrict__ xn,
        const float* __restrict__ wqkv, unsigned short* __restrict__ wqkvT,
        const float* __restrict__ wout, unsigned short* __restrict__ woutT) {
    __shared__ unsigned short tile[32][33];
    __shared__ float red[4][2];
    const int t = threadIdx.x;
    if (blockIdx.z == 2) {
        // ---- layernorm fp32 -> bf16 ----
        const int row = blockIdx.y * 128 + blockIdx.x;
        const size_t base = (size_t)row * DMODEL + t * 4;
        float4 v = *(const float4*)(x + base);
        float s  = v.x + v.y + v.z + v.w;
        float ss = v.x*v.x + v.y*v.y + v.z*v.z + v.w*v.w;
        for (int off = 32; off >= 1; off >>= 1) {
            s  += __shfl_xor(s,  off);
            ss += __shfl_xor(ss, off);
        }
        const int w = t >> 6, lane = t & 63;
        if (lane == 0) { red[w][0] = s; red[w][1] = ss; }
        __syncthreads();
        if (t == 0) {
            float S  = red[0][0] + red[1][0] + red[2][0] + red[3][0];
            float SS = red[0][1] + red[1][1] + red[2][1] + red[3][1];
            float mu  = S * (1.f / DMODEL);
            float var = SS * (1.f / DMODEL) - mu * mu;
            red[0][0] = mu; red[0][1] = rsqrtf(var + 1e-5f);
        }
        __syncthreads();
        const float mu = red[0][0], rstd = red[0][1];
        float4 g = *(const float4*)(gamma + t * 4);
        float4 bb = *(const float4*)(beta + t * 4);
        ushort4 o;
        o.x = f2bf((v.x - mu) * rstd * g.x + bb.x);
        o.y = f2bf((v.y - mu) * rstd * g.y + bb.y);
        o.z = f2bf((v.z - mu) * rstd * g.z + bb.z);
        o.w = f2bf((v.w - mu) * rstd * g.w + bb.w);
        *(ushort4*)(xn + base) = o;
        return;
    }
    // ---- transpose + fp32->bf16: out[c][r] = bf16(in[r][c]) ----
    const float* in; unsigned short* out; int rows, cols;
    if (blockIdx.z == 0) {
        if (blockIdx.x >= QKVN / 32) return;
        in = wqkv; out = wqkvT; rows = DMODEL; cols = QKVN;
    } else {
        if (blockIdx.x >= DMODEL / 32) return;
        in = wout; out = woutT; rows = INNER; cols = DMODEL;
    }
    const int bx = blockIdx.x * 32, by = blockIdx.y * 32;
    const int tx = t & 31, ty = t >> 5;
    for (int i = ty; i < 32; i += 8)
        tile[i][tx] = f2bf(in[(size_t)(by + i) * cols + bx + tx]);
    __syncthreads();
    for (int i = ty; i < 32; i += 8)
        out[(size_t)(bx + i) * rows + by + tx] = tile[tx][i];
}

// ------- QKV GEMM: 128x128 tile, BK=32, 3-buffer depth-2 prefetch (T4+T5) -------
// Counted-vmcnt pipeline (r12, proven -7us): raw s_barrier; each wave waits its
// OWN vmcnt(4) for the tile it is about to read BEFORE the barrier -- the newest
// prefetch (4 loads) stays in flight across it. Depth-2 into 3 rotating buffers.
// LDS = 48KB -> 3 blocks/CU; grid 768 = exactly 3/CU.
__global__ __launch_bounds__(256) void gemm_qkv(
        const unsigned short* __restrict__ A,    // xn [4096,1024]
        const unsigned short* __restrict__ Bt,   // wqkvT [3072,1024]
        unsigned short* __restrict__ qP,
        unsigned short* __restrict__ kP,
        unsigned short* __restrict__ vT) {
    const int K = DMODEL;
    __shared__ __align__(16) unsigned short smem[3 * 8192];  // 48KB: 3 x (A 4096 + B 4096)
    const int t = threadIdx.x;
    const int mBase = blockIdx.y * 128, nBase = blockIdx.x * 128;
    const int w = t >> 6, lane = t & 63, quad = lane >> 4, l16 = lane & 15;
    const int wm = (w >> 1) * 64, wn = (w & 1) * 64;
    const int srow = t >> 2, sch = t & 3;
    floatx4 acc[4][4];
    for (int mi = 0; mi < 4; mi++)
        for (int ni = 0; ni < 4; ni++) acc[mi][ni] = (floatx4)0.f;

    auto stage = [&](int k0, int bi) {      // 4 gl_lds16 per wave (A0,B0,A1,B1)
        unsigned short* sA = smem + bi * 8192;
        unsigned short* sB = sA + 4096;
        #pragma unroll
        for (int c = 0; c < 2; c++) {
            const int row = c * 64 + srow;
            const int gcol = (sch ^ ((row >> 1) & 3)) * 8;
            gl_lds16(&A[(size_t)(mBase + row) * K + k0 + gcol], &sA[(c * 256 + w * 64) * 8]);
            gl_lds16(&Bt[(size_t)(nBase + row) * K + k0 + gcol], &sB[(c * 256 + w * 64) * 8]);
        }
    };

    const int NK = K / 32;                  // 32
    stage(0, 0);
    stage(32, 1);
    for (int kk = 0; kk < NK; ++kk) {
        // own stage(kk) landed; newest prefetch (4 loads) stays in flight
        if (kk + 1 < NK) { asm volatile("s_waitcnt vmcnt(4)" ::: "memory"); }
        else             { asm volatile("s_waitcnt vmcnt(0)" ::: "memory"); }
        __builtin_amdgcn_sched_barrier(0);
        __builtin_amdgcn_s_barrier();
        const unsigned short* sA = smem + (kk % 3) * 8192;
        const unsigned short* sB = sA + 4096;
        bf16x8 af[4], bfv[4];
        #pragma unroll
        for (int mi = 0; mi < 4; mi++) {
            const int r = wm + mi * 16 + l16;
            af[mi] = *(const bf16x8*)&sA[r * 32 + (quad ^ ((r >> 1) & 3)) * 8];
        }
        #pragma unroll
        for (int ni = 0; ni < 4; ni++) {
            const int r = wn + ni * 16 + l16;
            bfv[ni] = *(const bf16x8*)&sB[r * 32 + (quad ^ ((r >> 1) & 3)) * 8];
        }
        if (kk + 2 < NK) stage((kk + 2) * 32, (kk + 2) % 3);
        __builtin_amdgcn_s_setprio(1);
        #pragma unroll
        for (int mi = 0; mi < 4; mi++)
            #pragma unroll
            for (int ni = 0; ni < 4; ni++)
                acc[mi][ni] = __builtin_amdgcn_mfma_f32_16x16x32_bf16(
                    af[mi], bfv[ni], acc[mi][ni], 0, 0, 0);
        __builtin_amdgcn_s_setprio(0);
    }
    __syncthreads();                        // all reads done before epilogue overlay
    const int reg = nBase >> 10;                  // block-uniform: 0=q 1=k 2=v
    if (reg == 2) {
        #pragma unroll
        for (int ni = 0; ni < 4; ni++) {
            const int col = nBase + wn + ni * 16 + l16;
            const int h = (col & 1023) >> 6, dh = col & 63;
            #pragma unroll
            for (int mi = 0; mi < 4; mi++) {
                const int row0 = mBase + wm + mi * 16 + quad * 4;
                const int b = row0 >> 11, s0 = row0 & 2047;
                ushort4 o;
                o.x = f2bf(acc[mi][ni][0]); o.y = f2bf(acc[mi][ni][1]);
                o.z = f2bf(acc[mi][ni][2]); o.w = f2bf(acc[mi][ni][3]);
                *(ushort4*)&vT[((size_t)(b * NH + h) * DHEAD + dh) * SEQ + s0] = o;
            }
        }
    } else {
        unsigned short* dst = (reg == 0) ? qP : kP;
        // fold DHEAD^-0.5 * log2(e) into q so attn softmax is a bare v_exp_f32
        const float scl = (reg == 0) ? 0.18033688011112042f : 1.f;
        const int hh = ((nBase + wn) & 1023) >> 6;     // wave-uniform head
        // 4 per-wave tb buffers (36.9KB) overlay the retired 48KB staging LDS.
        unsigned short* tb_ = smem + w * (64 * 72);
        #pragma unroll
        for (int mi = 0; mi < 4; mi++)
            #pragma unroll
            for (int ni = 0; ni < 4; ni++)
                #pragma unroll
                for (int i = 0; i < 4; i++)
                    tb_[(mi * 16 + quad * 4 + i) * 72 + ni * 16 + l16] =
                        f2bf(acc[mi][ni][i] * scl);
        asm volatile("s_waitcnt lgkmcnt(0)" ::: "memory");   // own-wave tb writes done
        const int row_g = mBase + wm + lane;
        const int b = row_g >> 11, sr = row_g & 2047;
        unsigned short* orow = dst + ((size_t)(b * NH + hh) * SEQ + sr) * DHEAD;
        #pragma unroll
        for (int c = 0; c < 8; c++)
            *(bf16x8*)&orow[c * 8] = *(const bf16x8*)&tb_[lane * 72 + c * 8];
    }
}

// ------- out GEMM: C = A*Bt^T + bias (fp32), 128x64, BK=32, 3-buffer T4+T5 -----
// (r13/r15 best config.) Counted-vmcnt pipeline; vmcnt(3). LDS = 36KB, grid 512.
__global__ __launch_bounds__(256) void gemm_out(
        const unsigned short* __restrict__ A,
        const unsigned short* __restrict__ Bt,
        float* __restrict__ C,
        const int M, const int N, const int K,
        const float* __restrict__ bias) {
    __shared__ __align__(16) unsigned short smem[3 * 6144];  // 36KB: 3 x (A 4096 + B 2048)
    const int t = threadIdx.x;
    const int mBase = blockIdx.y * 128, nBase = blockIdx.x * 64;
    const int w = t >> 6, lane = t & 63, quad = lane >> 4, l16 = lane & 15;
    const int wm = (w >> 1) * 64, wn = (w & 1) * 32;
    const int srow = t >> 2, sch = t & 3;
    floatx4 acc[4][2];
    for (int mi = 0; mi < 4; mi++)
        for (int ni = 0; ni < 2; ni++) acc[mi][ni] = (floatx4)0.f;

    auto stage = [&](int k0, int bi) {      // 3 gl_lds16 per wave (A0,A1,B)
        unsigned short* sA = smem + bi * 6144;
        unsigned short* sB = sA + 4096;
        #pragma unroll
        for (int c = 0; c < 2; c++) {
            const int row = c * 64 + srow;
            const int gcol = (sch ^ ((row >> 1) & 3)) * 8;
            gl_lds16(&A[(size_t)(mBase + row) * K + k0 + gcol], &sA[(c * 256 + w * 64) * 8]);
        }
        {
            const int gcol = (sch ^ ((srow >> 1) & 3)) * 8;
            gl_lds16(&Bt[(size_t)(nBase + srow) * K + k0 + gcol], &sB[(w * 64) * 8]);
        }
    };

    const int NK = K / 32;
    stage(0, 0);
    stage(32, 1);
    for (int kk = 0; kk < NK; ++kk) {
        if (kk + 1 < NK) { asm volatile("s_waitcnt vmcnt(3)" ::: "memory"); }
        else             { asm volatile("s_waitcnt vmcnt(0)" ::: "memory"); }
        __builtin_amdgcn_sched_barrier(0);
        __builtin_amdgcn_s_barrier();
        const unsigned short* sA = smem + (kk % 3) * 6144;
        const unsigned short* sB = sA + 4096;
        bf16x8 af[4], bfv[2];
        #pragma unroll
        for (int mi = 0; mi < 4; mi++) {
            const int r = wm + mi * 16 + l16;
            af[mi] = *(const bf16x8*)&sA[r * 32 + (quad ^ ((r >> 1) & 3)) * 8];
        }
        #pragma unroll
        for (int ni = 0; ni < 2; ni++) {
            const int r = wn + ni * 16 + l16;
            bfv[ni] = *(const bf16x8*)&sB[r * 32 + (quad ^ ((r >> 1) & 3)) * 8];
        }
        if (kk + 2 < NK) stage((kk + 2) * 32, (kk + 2) % 3);
        __builtin_amdgcn_s_setprio(1);
        #pragma unroll
        for (int mi = 0; mi < 4; mi++)
            #pragma unroll
            for (int ni = 0; ni < 2; ni++)
                acc[mi][ni] = __builtin_amdgcn_mfma_f32_16x16x32_bf16(
                    af[mi], bfv[ni], acc[mi][ni], 0, 0, 0);
        __builtin_amdgcn_s_setprio(0);
    }
    #pragma unroll
    for (int mi = 0; mi < 4; mi++)
        #pragma unroll
        for (int ni = 0; ni < 2; ni++) {
            const int col = nBase + wn + ni * 16 + l16;
            const float badd = bias ? bias[col] : 0.f;
            #pragma unroll
            for (int i = 0; i < 4; i++) {
                const int row = mBase + wm + mi * 16 + quad * 4 + i;
                C[(size_t)row * N + col] = acc[mi][ni][i] + badd;
            }
        }
}

// ------- flash attention: 32x32 MFMA + in-reg P, 8-wave 128q x 128kv tiles ------
// r17: ATT_KB 64 -> 128. Each barrier-iteration now processes 2 kv-sub-tiles of
// the verified inner loop -> barrier events halve (32 -> 16) and per-wave MFMA
// ILP doubles, with DMA total unchanged. LDS = 64KB (2buf K[128][64] +
// 2buf V[64][128]) -> 2 blocks/CU x 8 waves = 16 waves/CU (TLP unchanged).
// V staging reshaped for stride-128 rows: 4 dh-rows x 16 chunks per instruction,
// source pre-swizzled chunk^(row&7) == read-side swizzle (both-sides rule).
__global__ __launch_bounds__(512, 4) void attn_kernel(
        const unsigned short* __restrict__ qP,
        const unsigned short* __restrict__ kP,
        const unsigned short* __restrict__ vT,
        unsigned short* __restrict__ aout) {   // [4096][1024] bf16
    __shared__ __align__(16) unsigned short kvs[32768];  // 64KB: sK[2][8192] ++ sV[2][8192]
    unsigned short* sK0 = kvs;            // K tile: [128 kv][64 dh], buf stride 8192
    unsigned short* sV0 = kvs + 16384;    // V tile: [64 dh][128 kv], buf stride 8192
    const int t = threadIdx.x, w = t >> 6, lane = t & 63;
    const int l32 = lane & 31, half = lane >> 5;
    const int qq = w & 3, kh = w >> 2;
    // XCD-aware remap: grid 512 = 8 XCD x 64 slots; 4 bh x 16 qb per XCD.
    const int bid = blockIdx.x;
    const int xcd = bid & 7, slot = bid >> 3;
    const int bh = xcd * 4 + (slot >> 4);
    const int qb = slot & 15;
    const int b = bh >> 4, h = bh & 15;
    const int qbase = qb * ATT_QB + qq * 32;

    bf16x8 qf[4];
    #pragma unroll
    for (int kd = 0; kd < 4; kd++)
        qf[kd] = *(const bf16x8*)&qP[
            ((size_t)bh * SEQ + qbase + l32) * DHEAD + kd * 16 + half * 8];

    floatx16 oac[2];
    oac[0] = (floatx16)0.f; oac[1] = (floatx16)0.f;
    float lS = 0.f;

    const unsigned short* kb = kP + (size_t)bh * SEQ * DHEAD;
    const unsigned short* vb = vT + (size_t)bh * DHEAD * SEQ;
    const int r8 = lane >> 3, sw8k = ((lane & 7) ^ r8) * 8;  // K staging swizzle
    const int vrow_off = lane >> 4, vchunk = lane & 15;      // V staging lane map

    auto stage = [&](int it, int bi) {
        const int kv0 = it * ATT_KB;
        #pragma unroll
        for (int ii = 0; ii < 2; ii++) {
            // K: 8 kv-rows x 64 dh per instruction (row&7 == lane>>3)
            const int krow = w * 16 + ii * 8 + r8;           // 0..127
            gl_lds16(kb + (size_t)(kv0 + krow) * DHEAD + sw8k,
                     (void*)&sK0[bi * 8192 + (w * 16 + ii * 8) * 64]);
            // V: 4 dh-rows x 16 kv-chunks per instruction
            const int dh0 = w * 8 + ii * 4;
            const int vrow = dh0 + vrow_off;                 // 0..63
            const int vcol = ((vchunk ^ (vrow & 7)) * 8);    // pre-swizzled source
            gl_lds16(vb + (size_t)vrow * SEQ + kv0 + vcol,
                     (void*)&sV0[bi * 8192 + dh0 * 128]);
        }
    };
    stage(0, 0);

    const int NIT = SEQ / ATT_KB;      // 16
    for (int it = 0; it < NIT; ++it) {
        __syncthreads();               // staging of tile `it` landed (all waves)
        const int bi = it & 1;
        if (it + 1 < NIT) stage(it + 1, bi ^ 1);   // writes buf^1: disjoint

        #pragma unroll
        for (int ks = 0; ks < 2; ks++) {
            // ---- K fragments: rows kh*64 + ks*32 + l32 ----
            bf16x8 kf[4];
            const int r = kh * 64 + ks * 32 + l32;   // r&7 == l32&7
            #pragma unroll
            for (int kd = 0; kd < 4; kd++)
                kf[kd] = *(const bf16x8*)&sK0[bi * 8192 + r * 64 +
                                              8 * ((2 * kd + half) ^ (l32 & 7))];

            floatx16 sv = (floatx16)0.f;
            __builtin_amdgcn_s_setprio(1);
            #pragma unroll
            for (int kd = 0; kd < 4; kd++)
                sv = __builtin_amdgcn_mfma_f32_32x32x16_bf16(kf[kd], qf[kd], sv, 0, 0, 0);
            __builtin_amdgcn_s_setprio(0);

            float p[16];
            #pragma unroll
            for (int i = 0; i < 16; i++) p[i] = fexp2(sv[i]);
            {
                float s = 0.f;
                #pragma unroll
                for (int i = 0; i < 16; i++) s += p[i];
                s += __shfl_xor(s, 32);    // partner half covers other 16 rows
                lS += s;
            }

            bf16x8 pf[2];
            #pragma unroll
            for (int kd = 0; kd < 2; kd++) {
                const int base = kd * 8;
                unsigned int c01 = pk2(p[base + 0], p[base + 1]);
                unsigned int c23 = pk2(p[base + 2], p[base + 3]);
                unsigned int c45 = pk2(p[base + 4], p[base + 5]);
                unsigned int c67 = pk2(p[base + 6], p[base + 7]);
                asm("v_permlane32_swap_b32 %0, %1" : "+v"(c01), "+v"(c45));
                asm("v_permlane32_swap_b32 %0, %1" : "+v"(c23), "+v"(c67));
                union { unsigned int u[4]; bf16x8 v; } fr;
                fr.u[0] = c01; fr.u[1] = c23; fr.u[2] = c45; fr.u[3] = c67;
                pf[kd] = fr.v;
            }

            __builtin_amdgcn_s_setprio(1);
            #pragma unroll
            for (int dt = 0; dt < 2; dt++)
                #pragma unroll
                for (int kd = 0; kd < 2; kd++) {
                    const int rr = dt * 32 + l32;      // dh row, rr&7 == l32&7
                    bf16x8 vf = *(const bf16x8*)&sV0[bi * 8192 + rr * 128 +
                        8 * ((kh * 8 + ks * 4 + kd * 2 + half) ^ (l32 & 7))];
                    oac[dt] = __builtin_amdgcn_mfma_f32_32x32x16_bf16(vf, pf[kd], oac[dt], 0, 0, 0);
                }
            __builtin_amdgcn_s_setprio(0);
        }
    }

    // ---- cross-wave combine over kv-halves (overlays retired kvs) ----
    __syncthreads();
    float* redO = (float*)kvs;                 // [4 qq][64 lanes][32 f32] = 32KB
    float* redL = (float*)(kvs + 16384);       // [4 qq][32 q] f32 (retired sV area)
    if (kh == 1) {
        #pragma unroll
        for (int dt = 0; dt < 2; dt++)
            #pragma unroll
            for (int g = 0; g < 4; g++) {
                const int c = dt * 4 + g;
                float4 o4;
                o4.x = oac[dt][g * 4 + 0]; o4.y = oac[dt][g * 4 + 1];
                o4.z = oac[dt][g * 4 + 2]; o4.w = oac[dt][g * 4 + 3];
                *(float4*)&redO[((size_t)qq * 64 + lane) * 32 + 4 * (c ^ (lane & 7))] = o4;
            }
        if (half == 0) redL[qq * 32 + l32] = lS;
    }
    __syncthreads();
    if (kh == 0) {
        #pragma unroll
        for (int dt = 0; dt < 2; dt++)
            #pragma unroll
            for (int g = 0; g < 4; g++) {
                const int c = dt * 4 + g;
                float4 o4 = *(const float4*)&redO[
                    ((size_t)qq * 64 + lane) * 32 + 4 * (c ^ (lane & 7))];
                oac[dt][g * 4 + 0] += o4.x; oac[dt][g * 4 + 1] += o4.y;
                oac[dt][g * 4 + 2] += o4.z; oac[dt][g * 4 + 3] += o4.w;
            }
        lS += redL[qq * 32 + l32];
        const float rl = 1.f / lS;
        unsigned short* orow = aout + ((size_t)(b * SEQ + qbase + l32)) * INNER + h * DHEAD;
        #pragma unroll
        for (int dt = 0; dt < 2; dt++)
            #pragma unroll
            for (int g = 0; g < 4; g++) {
                ushort4 o;
                o.x = f2bf(oac[dt][g * 4 + 0] * rl);
                o.y = f2bf(oac[dt][g * 4 + 1] * rl);
                o.z = f2bf(oac[dt][g * 4 + 2] * rl);
                o.w = f2bf(oac[dt][g * 4 + 3] * rl);
                *(ushort4*)&orow[dt * 32 + g * 8 + half * 4] = o;
            }
    }
}

extern "C" void kernel_launch(void* const* d_in, const int* in_sizes, int n_in,
                              void* d_out, int out_size, void* d_ws, size_t ws_size,
                              hipStream_t stream) {
    const float* x     = (const float*)d_in[0];
    const float* gamma = (const float*)d_in[1];
    const float* beta  = (const float*)d_in[2];
    const float* wqkv  = (const float*)d_in[3];
    const float* wout  = (const float*)d_in[4];
    const float* bout  = (const float*)d_in[5];
    float* out = (float*)d_out;

    unsigned short* ws     = (unsigned short*)d_ws;
    unsigned short* xn     = ws;                                  // 4096x1024
    unsigned short* wqkvT  = xn     + (size_t)ROWS * DMODEL;      // 3072x1024
    unsigned short* qPb    = wqkvT  + (size_t)QKVN * DMODEL;      // 32x2048x64
    unsigned short* kPb    = qPb    + (size_t)NBATCH * NH * SEQ * DHEAD;
    unsigned short* vTb    = kPb    + (size_t)NBATCH * NH * SEQ * DHEAD;
    unsigned short* attnO  = vTb    + (size_t)NBATCH * NH * SEQ * DHEAD; // 4096x1024
    unsigned short* woutT  = attnO  + (size_t)ROWS * INNER;       // 1024x1024

    // z=0: wqkv transpose (x<96); z=1: wout transpose (x<32); z=2: LN (128x32=4096 rows)
    prep_kernel<<<dim3(128, 32, 3), 256, 0, stream>>>(
        x, gamma, beta, xn, wqkv, wqkvT, wout, woutT);
    gemm_qkv<<<dim3(QKVN / 128, ROWS / 128), 256, 0, stream>>>(xn, wqkvT, qPb, kPb, vTb);
    attn_kernel<<<dim3((SEQ / ATT_QB) * NBATCH * NH), 512, 0, stream>>>(
        qPb, kPb, vTb, attnO);
    gemm_out<<<dim3(DMODEL / 64, ROWS / 128), 256, 0, stream>>>(
        attnO, woutT, out, ROWS, DMODEL, INNER, bout);
}